// Round 19
// baseline (162.375 us; speedup 1.0000x reference)
//
#include <hip/hip_runtime.h>

// Problem: H=W=384, F=K=256. M = 147456 rows.
// out[m,f] = sum_k d[m,k] * y[k,f],  y = x[stations] @ W  (256x256, tiny)
#define FF 256
#define KK 256
#define RR 16                  // rows per stripe
#define STRIPES 8              // stripes per block -> 128 rows/block
#define NBLK 2304              // (147456/128 rowgroups) * 2 col-halves
#define HALFC 128              // cols per block (half of FF)

typedef __attribute__((ext_vector_type(8))) short bf16x8;   // 8 bf16 (4 VGPR)
typedef __attribute__((ext_vector_type(4))) float f32x4;    // MFMA C/D frag
typedef __attribute__((ext_vector_type(4))) short short4v;  // 4 bf16 (8 B)

// float -> bf16 bits, round-to-nearest-even
__device__ inline short f2bf(float x) {
    unsigned u = __float_as_uint(x);
    unsigned r = u + 0x7FFFu + ((u >> 16) & 1u);
    return (short)(r >> 16);
}

// Kernel 1: y[k][f] = sum_j x[sx[k],sy[k],j] * W[j][f], stored bf16 in
// FRAGMENT ORDER so kernel-2 B loads are lane-contiguous 16B/lane:
//   idx(k,f) = ((f>>4)*8 + (k>>5))*512 + (((k>>3)&3)*16 + (f&15))*8 + (k&7)
__global__ __launch_bounds__(256) void station_kernel(
        const float* __restrict__ x, const float* __restrict__ W,
        const int* __restrict__ sx, const int* __restrict__ sy,
        short* __restrict__ yp) {
    __shared__ float xrow[FF];
    const int k = blockIdx.x;
    const int f = threadIdx.x;
    const long base = ((long)sx[k] * 384 + (long)sy[k]) * FF;
    xrow[f] = x[base + f];
    __syncthreads();
    float acc = 0.f;
    #pragma unroll 8
    for (int j = 0; j < FF; ++j)
        acc += xrow[j] * W[j * FF + f];   // coalesced across f
    const int idx = ((f >> 4) * 8 + (k >> 5)) * 512
                  + (((k >> 3) & 3) * 16 + (f & 15)) * 8 + (k & 7);
    yp[idx] = f2bf(acc);
}

// Kernel 2: R13 cadence exactly (2 x __syncthreads per stripe, proven 77.6us),
// with (a) STRIPES 4->8 to amortize the bfrag+prologue cost over 2x rows,
// (b) ldsC scatter XOR (col ^= lg<<5) killing the 4-way write bank conflict.
__global__ __launch_bounds__(256, 4) void gemm_kernel(
        const float* __restrict__ d, const short* __restrict__ yp,
        float* __restrict__ out) {
    __shared__ __align__(16) short ldsA[2][RR * KK];   // 2 x 8 KB A, swizzled
    __shared__ __align__(16) float ldsC[RR * HALFC];   // 8 KB C staging
    const int t    = threadIdx.x;
    const int lane = t & 63;
    const int wid  = t >> 6;          // 0..3: 32-col slice within the half
    const int l15  = lane & 15;
    const int lg   = lane >> 4;       // 0..3: k-subgroup

    // Bijective XCD swizzle (NBLK % 8 == 0): row-sharing col-half pairs co-XCD.
    const int work = (blockIdx.x & 7) * (NBLK / 8) + (blockIdx.x >> 3);
    const int half = work & 1;                  // col half: 0..1 (128 cols)
    const long mblk = (long)(work >> 1) * (RR * STRIPES);

    char* lb0 = (char*)ldsA[0];
    char* lb1 = (char*)ldsA[1];

    // ---- B fragments: 16 x 16B/lane coalesced loads, once per block ----
    bf16x8 bfrag[8][2];
    #pragma unroll
    for (int kf = 0; kf < 8; ++kf)
        #pragma unroll
        for (int nf = 0; nf < 2; ++nf) {
            const int g = half * 8 + wid * 2 + nf;   // 16-col group 0..15
            bfrag[kf][nf] = *(const bf16x8*)(yp + ((g * 8 + kf) << 9) + (lane << 3));
        }
    // Anti-remat value barrier: keep them register/AGPR-resident.
    asm volatile("" :
        "+v"(bfrag[0][0]), "+v"(bfrag[0][1]), "+v"(bfrag[1][0]), "+v"(bfrag[1][1]),
        "+v"(bfrag[2][0]), "+v"(bfrag[2][1]), "+v"(bfrag[3][0]), "+v"(bfrag[3][1]),
        "+v"(bfrag[4][0]), "+v"(bfrag[4][1]), "+v"(bfrag[5][0]), "+v"(bfrag[5][1]),
        "+v"(bfrag[6][0]), "+v"(bfrag[6][1]), "+v"(bfrag[7][0]), "+v"(bfrag[7][1]));

    // staging geometry: pass p covers rows p*4 + (t>>6), lane writes 8B at
    // col-byte 8*(t&63). 4 passes x 256 thr x 4 floats = 4096 = 16 rows.
    const int srow0 = t >> 6;
    const int scol  = (t & 63) * 8;

    // ---- prologue: load + stage stripe 0 into buf0 ----
    float4 pv[4];
    {
        const float* dp = d + mblk * KK;
        #pragma unroll
        for (int p = 0; p < 4; ++p)
            pv[p] = *(const float4*)(dp + (p * 256 + t) * 4);
        #pragma unroll
        for (int p = 0; p < 4; ++p) {
            const int row = p * 4 + srow0;
            int byte = row * 512 + scol;
            byte ^= (row & 7) << 4;               // bank swizzle (G4)
            short4v b;
            b.x = f2bf(pv[p].x); b.y = f2bf(pv[p].y);
            b.z = f2bf(pv[p].z); b.w = f2bf(pv[p].w);
            *(short4v*)(lb0 + byte) = b;
        }
    }
    __syncthreads();

    for (int s = 0; s < STRIPES; ++s) {
        const long m0 = mblk + (long)s * RR;
        char* cur = (s & 1) ? lb1 : lb0;
        char* nxt = (s & 1) ? lb0 : lb1;

        // (1) issue next stripe's global loads — vmcnt waits land at stage
        if (s + 1 < STRIPES) {
            const float* dp = d + (m0 + RR) * KK;
            #pragma unroll
            for (int p = 0; p < 4; ++p)
                pv[p] = *(const float4*)(dp + (p * 256 + t) * 4);
        }

        // (2) compute current stripe: A from LDS, B resident
        f32x4 acc[2];
        #pragma unroll
        for (int nf = 0; nf < 2; ++nf)
            #pragma unroll
            for (int q = 0; q < 4; ++q) acc[nf][q] = 0.f;

        #pragma unroll
        for (int kf = 0; kf < 8; ++kf) {
            const int cb = kf * 64 + lg * 16;
            const int xo = (l15 & 7) << 4;
            bf16x8 a0 = *(const bf16x8*)(cur + ((l15 * 512 + cb) ^ xo));
            #pragma unroll
            for (int nf = 0; nf < 2; ++nf)
                acc[nf] = __builtin_amdgcn_mfma_f32_16x16x32_bf16(
                              a0, bfrag[kf][nf], acc[nf], 0, 0, 0);
        }

        // (3) C fragments -> LDS tile; col XOR'd by lg<<5 so the 4 lanes
        // lg=0..3 (rows 4 apart, same bank pre-XOR) hit distinct banks.
        #pragma unroll
        for (int nf = 0; nf < 2; ++nf)
            #pragma unroll
            for (int q = 0; q < 4; ++q)
                ldsC[(lg * 4 + q) * HALFC
                     + ((wid * 32 + nf * 16 + l15) ^ (lg << 5))] = acc[nf][q];
        __syncthreads();

        // (4) stream C tile out LINEARLY (un-XOR on read; still full-row
        // reads -> same banks as before). Per wave-instr: 2 rows x 512 B.
        #pragma unroll
        for (int p = 0; p < 2; ++p) {
            const int e   = p * 1024 + t * 4;        // element index in tile
            const int row = e >> 7;
            const int col = e & 127;
            const float4 v = *(const float4*)(ldsC + row * HALFC
                                              + (col ^ (((row >> 2) & 3) << 5)));
            *(float4*)(out + (m0 + row) * FF + half * HALFC + col) = v;
        }

        // (5) convert + LDS-write pending A stripe into nxt
        if (s + 1 < STRIPES) {
            #pragma unroll
            for (int p = 0; p < 4; ++p) {
                const int row = p * 4 + srow0;
                int byte = row * 512 + scol;
                byte ^= (row & 7) << 4;
                short4v b;
                b.x = f2bf(pv[p].x); b.y = f2bf(pv[p].y);
                b.z = f2bf(pv[p].z); b.w = f2bf(pv[p].w);
                *(short4v*)(nxt + byte) = b;
            }
        }

        // (6) close the stripe
        __syncthreads();
    }
}

extern "C" void kernel_launch(void* const* d_in, const int* in_sizes, int n_in,
                              void* d_out, int out_size, void* d_ws, size_t ws_size,
                              hipStream_t stream) {
    const float* x  = (const float*)d_in[0];
    const float* d  = (const float*)d_in[1];
    const float* W  = (const float*)d_in[2];
    const int*   sx = (const int*)d_in[3];
    const int*   sy = (const int*)d_in[4];
    float* out = (float*)d_out;
    short* yp  = (short*)d_ws;   // 256*256 bf16 = 128 KB packed fragment buffer

    station_kernel<<<dim3(KK), dim3(FF), 0, stream>>>(x, W, sx, sy, yp);
    gemm_kernel<<<dim3(NBLK), dim3(256), 0, stream>>>(d, yp, out);
}

// Round 20
// 76.483 us; speedup vs baseline: 2.1230x; 2.1230x over previous
//
#include <hip/hip_runtime.h>

// Problem: H=W=384, F=K=256. M = 147456 rows.
// out[m,f] = sum_k d[m,k] * y[k,f],  y = x[stations] @ W  (256x256, tiny)
#define FF 256
#define KK 256
#define RR 16                  // rows per stripe
#define STRIPES 4              // stripes per block -> 64 rows/block
#define NBLK 4608              // (147456/64 rowgroups) * 2 col-halves
#define HALFC 128              // cols per block (half of FF)

typedef __attribute__((ext_vector_type(8))) short bf16x8;   // 8 bf16 (4 VGPR)
typedef __attribute__((ext_vector_type(4))) float f32x4;    // MFMA C/D frag
typedef __attribute__((ext_vector_type(4))) short short4v;  // 4 bf16 (8 B)

// float -> bf16 bits, round-to-nearest-even
__device__ inline short f2bf(float x) {
    unsigned u = __float_as_uint(x);
    unsigned r = u + 0x7FFFu + ((u >> 16) & 1u);
    return (short)(r >> 16);
}

// Kernel 1: y[k][f] = sum_j x[sx[k],sy[k],j] * W[j][f], stored bf16 in
// FRAGMENT ORDER so kernel-2 B loads are lane-contiguous 16B/lane:
//   idx(k,f) = ((f>>4)*8 + (k>>5))*512 + (((k>>3)&3)*16 + (f&15))*8 + (k&7)
__global__ __launch_bounds__(256) void station_kernel(
        const float* __restrict__ x, const float* __restrict__ W,
        const int* __restrict__ sx, const int* __restrict__ sy,
        short* __restrict__ yp) {
    __shared__ float xrow[FF];
    const int k = blockIdx.x;
    const int f = threadIdx.x;
    const long base = ((long)sx[k] * 384 + (long)sy[k]) * FF;
    xrow[f] = x[base + f];
    __syncthreads();
    float acc = 0.f;
    #pragma unroll 8
    for (int j = 0; j < FF; ++j)
        acc += xrow[j] * W[j * FF + f];   // coalesced across f
    const int idx = ((f >> 4) * 8 + (k >> 5)) * 512
                  + (((k >> 3) & 3) * 16 + (f & 15)) * 8 + (k & 7);
    yp[idx] = f2bf(acc);
}

// Kernel 2 (round-13 optimum, 77.6 us measured): 256-thread blocks, 4 waves;
// block = 64 rows x 128-col half; bfrag[8][2] loaded once (AGPR-parked);
// A double-buffered in bf16 LDS (XOR-swizzled, conflict-free ds_read_b128);
// T14 issue-early/convert-late staging; C via LDS transpose tile so global
// writes are full-cache-line linear streams (the proven +13% lever).
__global__ __launch_bounds__(256, 4) void gemm_kernel(
        const float* __restrict__ d, const short* __restrict__ yp,
        float* __restrict__ out) {
    __shared__ __align__(16) short ldsA[2][RR * KK];   // 2 x 8 KB A, swizzled
    __shared__ __align__(16) float ldsC[RR * HALFC];   // 8 KB C staging
    const int t    = threadIdx.x;
    const int lane = t & 63;
    const int wid  = t >> 6;          // 0..3: 32-col slice within the half
    const int l15  = lane & 15;
    const int lg   = lane >> 4;       // 0..3: k-subgroup

    // Bijective XCD swizzle (NBLK % 8 == 0): row-sharing col-half pairs co-XCD.
    const int work = (blockIdx.x & 7) * (NBLK / 8) + (blockIdx.x >> 3);
    const int half = work & 1;                  // col half: 0..1 (128 cols)
    const long mblk = (long)(work >> 1) * (RR * STRIPES);

    char* lb0 = (char*)ldsA[0];
    char* lb1 = (char*)ldsA[1];

    // ---- B fragments: 16 x 16B/lane coalesced loads, once per block ----
    bf16x8 bfrag[8][2];
    #pragma unroll
    for (int kf = 0; kf < 8; ++kf)
        #pragma unroll
        for (int nf = 0; nf < 2; ++nf) {
            const int g = half * 8 + wid * 2 + nf;   // 16-col group 0..15
            bfrag[kf][nf] = *(const bf16x8*)(yp + ((g * 8 + kf) << 9) + (lane << 3));
        }
    // Anti-remat value barrier: keep them register/AGPR-resident.
    asm volatile("" :
        "+v"(bfrag[0][0]), "+v"(bfrag[0][1]), "+v"(bfrag[1][0]), "+v"(bfrag[1][1]),
        "+v"(bfrag[2][0]), "+v"(bfrag[2][1]), "+v"(bfrag[3][0]), "+v"(bfrag[3][1]),
        "+v"(bfrag[4][0]), "+v"(bfrag[4][1]), "+v"(bfrag[5][0]), "+v"(bfrag[5][1]),
        "+v"(bfrag[6][0]), "+v"(bfrag[6][1]), "+v"(bfrag[7][0]), "+v"(bfrag[7][1]));

    // staging geometry: pass p covers rows p*4 + (t>>6), lane writes 8B at
    // col-byte 8*(t&63). 4 passes x 256 thr x 4 floats = 4096 = 16 rows.
    const int srow0 = t >> 6;
    const int scol  = (t & 63) * 8;

    // ---- prologue: load + stage stripe 0 into buf0 ----
    float4 pv[4];
    {
        const float* dp = d + mblk * KK;
        #pragma unroll
        for (int p = 0; p < 4; ++p)
            pv[p] = *(const float4*)(dp + (p * 256 + t) * 4);
        #pragma unroll
        for (int p = 0; p < 4; ++p) {
            const int row = p * 4 + srow0;
            int byte = row * 512 + scol;
            byte ^= (row & 7) << 4;               // bank swizzle (G4)
            short4v b;
            b.x = f2bf(pv[p].x); b.y = f2bf(pv[p].y);
            b.z = f2bf(pv[p].z); b.w = f2bf(pv[p].w);
            *(short4v*)(lb0 + byte) = b;
        }
    }
    __syncthreads();

    for (int s = 0; s < STRIPES; ++s) {
        const long m0 = mblk + (long)s * RR;
        char* cur = (s & 1) ? lb1 : lb0;
        char* nxt = (s & 1) ? lb0 : lb1;

        // (1) issue next stripe's global loads — vmcnt waits land at stage
        if (s + 1 < STRIPES) {
            const float* dp = d + (m0 + RR) * KK;
            #pragma unroll
            for (int p = 0; p < 4; ++p)
                pv[p] = *(const float4*)(dp + (p * 256 + t) * 4);
        }

        // (2) compute current stripe: A from LDS, B resident
        f32x4 acc[2];
        #pragma unroll
        for (int nf = 0; nf < 2; ++nf)
            #pragma unroll
            for (int q = 0; q < 4; ++q) acc[nf][q] = 0.f;

        #pragma unroll
        for (int kf = 0; kf < 8; ++kf) {
            const int cb = kf * 64 + lg * 16;
            const int xo = (l15 & 7) << 4;
            bf16x8 a0 = *(const bf16x8*)(cur + ((l15 * 512 + cb) ^ xo));
            #pragma unroll
            for (int nf = 0; nf < 2; ++nf)
                acc[nf] = __builtin_amdgcn_mfma_f32_16x16x32_bf16(
                              a0, bfrag[kf][nf], acc[nf], 0, 0, 0);
        }

        // (3) C fragments -> LDS tile (scatter), then barrier
        #pragma unroll
        for (int nf = 0; nf < 2; ++nf)
            #pragma unroll
            for (int q = 0; q < 4; ++q)
                ldsC[(lg * 4 + q) * HALFC + wid * 32 + nf * 16 + l15]
                    = acc[nf][q];
        __syncthreads();

        // (4) stream C tile out LINEARLY: per wave-instruction 2 rows x
        // 512 B contiguous (4 full cache lines) — memcpy-like write stream.
        #pragma unroll
        for (int p = 0; p < 2; ++p) {
            const int e = p * 1024 + t * 4;          // element index in tile
            const float4 v = *(const float4*)(ldsC + e);
            *(float4*)(out + (m0 + (e >> 7)) * FF + half * HALFC + (e & 127)) = v;
        }

        // (5) convert + LDS-write pending A stripe into nxt
        if (s + 1 < STRIPES) {
            #pragma unroll
            for (int p = 0; p < 4; ++p) {
                const int row = p * 4 + srow0;
                int byte = row * 512 + scol;
                byte ^= (row & 7) << 4;
                short4v b;
                b.x = f2bf(pv[p].x); b.y = f2bf(pv[p].y);
                b.z = f2bf(pv[p].z); b.w = f2bf(pv[p].w);
                *(short4v*)(nxt + byte) = b;
            }
        }

        // (6) close the stripe
        __syncthreads();
    }
}

extern "C" void kernel_launch(void* const* d_in, const int* in_sizes, int n_in,
                              void* d_out, int out_size, void* d_ws, size_t ws_size,
                              hipStream_t stream) {
    const float* x  = (const float*)d_in[0];
    const float* d  = (const float*)d_in[1];
    const float* W  = (const float*)d_in[2];
    const int*   sx = (const int*)d_in[3];
    const int*   sy = (const int*)d_in[4];
    float* out = (float*)d_out;
    short* yp  = (short*)d_ws;   // 256*256 bf16 = 128 KB packed fragment buffer

    station_kernel<<<dim3(KK), dim3(FF), 0, stream>>>(x, W, sx, sy, yp);
    gemm_kernel<<<dim3(NBLK), dim3(256), 0, stream>>>(d, yp, out);
}

// Round 21
// 75.929 us; speedup vs baseline: 2.1385x; 1.0073x over previous
//
#include <hip/hip_runtime.h>

// Problem: H=W=384, F=K=256. M = 147456 rows.
// out[m,f] = sum_k d[m,k] * y[k,f],  y = x[stations] @ W  (256x256, tiny)
#define FF 256
#define KK 256
#define RR 32                  // rows per stripe (2x R13)
#define STRIPES 4              // stripes per block -> 128 rows/block
#define NBLK 2304              // (147456/128 rowgroups) * 2 col-halves
#define HALFC 128              // cols per block (half of FF)

typedef __attribute__((ext_vector_type(8))) short bf16x8;   // 8 bf16 (4 VGPR)
typedef __attribute__((ext_vector_type(4))) float f32x4;    // MFMA C/D frag
typedef __attribute__((ext_vector_type(4))) short short4v;  // 4 bf16 (8 B)

// float -> bf16 bits, round-to-nearest-even
__device__ inline short f2bf(float x) {
    unsigned u = __float_as_uint(x);
    unsigned r = u + 0x7FFFu + ((u >> 16) & 1u);
    return (short)(r >> 16);
}

// Kernel 1: y[k][f] = sum_j x[sx[k],sy[k],j] * W[j][f], stored bf16 in
// FRAGMENT ORDER so kernel-2 B loads are lane-contiguous 16B/lane:
//   idx(k,f) = ((f>>4)*8 + (k>>5))*512 + (((k>>3)&3)*16 + (f&15))*8 + (k&7)
__global__ __launch_bounds__(256) void station_kernel(
        const float* __restrict__ x, const float* __restrict__ W,
        const int* __restrict__ sx, const int* __restrict__ sy,
        short* __restrict__ yp) {
    __shared__ float xrow[FF];
    const int k = blockIdx.x;
    const int f = threadIdx.x;
    const long base = ((long)sx[k] * 384 + (long)sy[k]) * FF;
    xrow[f] = x[base + f];
    __syncthreads();
    float acc = 0.f;
    #pragma unroll 8
    for (int j = 0; j < FF; ++j)
        acc += xrow[j] * W[j * FF + f];   // coalesced across f
    const int idx = ((f >> 4) * 8 + (k >> 5)) * 512
                  + (((k >> 3) & 3) * 16 + (f & 15)) * 8 + (k & 7);
    yp[idx] = f2bf(acc);
}

// Kernel 2: R13's proven components (bf16 XOR-swizzled A LDS, AGPR-parked
// bfrag, T14 issue-early/convert-late, LDS-linearized C stores) at RR=32:
// halves the barrier-rendezvous rate per row (2/32rows vs R13's 4/32rows)
// and doubles bfrag/prologue amortization (128 rows/block).
__global__ __launch_bounds__(256, 3) void gemm_kernel(
        const float* __restrict__ d, const short* __restrict__ yp,
        float* __restrict__ out) {
    __shared__ __align__(16) short ldsA[2][RR * KK];   // 2 x 16 KB A, swizzled
    __shared__ __align__(16) float ldsC[RR * HALFC];   // 16 KB C staging
    const int t    = threadIdx.x;
    const int lane = t & 63;
    const int wid  = t >> 6;          // 0..3: 32-col slice within the half
    const int l15  = lane & 15;
    const int lg   = lane >> 4;       // 0..3: k-subgroup

    // Bijective XCD swizzle (NBLK % 8 == 0): row-sharing col-half pairs co-XCD.
    const int work = (blockIdx.x & 7) * (NBLK / 8) + (blockIdx.x >> 3);
    const int half = work & 1;                  // col half: 0..1 (128 cols)
    const long mblk = (long)(work >> 1) * (RR * STRIPES);

    char* lb0 = (char*)ldsA[0];
    char* lb1 = (char*)ldsA[1];

    // ---- B fragments: 16 x 16B/lane coalesced loads, once per block ----
    bf16x8 bfrag[8][2];
    #pragma unroll
    for (int kf = 0; kf < 8; ++kf)
        #pragma unroll
        for (int nf = 0; nf < 2; ++nf) {
            const int g = half * 8 + wid * 2 + nf;   // 16-col group 0..15
            bfrag[kf][nf] = *(const bf16x8*)(yp + ((g * 8 + kf) << 9) + (lane << 3));
        }
    // Anti-remat value barrier: keep them register/AGPR-resident.
    asm volatile("" :
        "+v"(bfrag[0][0]), "+v"(bfrag[0][1]), "+v"(bfrag[1][0]), "+v"(bfrag[1][1]),
        "+v"(bfrag[2][0]), "+v"(bfrag[2][1]), "+v"(bfrag[3][0]), "+v"(bfrag[3][1]),
        "+v"(bfrag[4][0]), "+v"(bfrag[4][1]), "+v"(bfrag[5][0]), "+v"(bfrag[5][1]),
        "+v"(bfrag[6][0]), "+v"(bfrag[6][1]), "+v"(bfrag[7][0]), "+v"(bfrag[7][1]));

    // staging geometry: pass p covers rows p*4 + (t>>6), lane writes 8B at
    // col-byte 8*(t&63). 8 passes x 256 thr x 4 floats = 8192 = 32 rows.
    const int srow0 = t >> 6;
    const int scol  = (t & 63) * 8;

    // ---- prologue: load + stage stripe 0 into buf0 ----
    float4 pv[8];
    {
        const float* dp = d + mblk * KK;
        #pragma unroll
        for (int p = 0; p < 8; ++p)
            pv[p] = *(const float4*)(dp + (p * 256 + t) * 4);
        #pragma unroll
        for (int p = 0; p < 8; ++p) {
            const int row = p * 4 + srow0;
            int byte = row * 512 + scol;
            byte ^= (row & 7) << 4;               // bank swizzle (G4)
            short4v b;
            b.x = f2bf(pv[p].x); b.y = f2bf(pv[p].y);
            b.z = f2bf(pv[p].z); b.w = f2bf(pv[p].w);
            *(short4v*)(lb0 + byte) = b;
        }
    }
    __syncthreads();

    for (int s = 0; s < STRIPES; ++s) {
        const long m0 = mblk + (long)s * RR;
        char* cur = (s & 1) ? lb1 : lb0;
        char* nxt = (s & 1) ? lb0 : lb1;

        // (1) issue next stripe's global loads — vmcnt waits land at stage
        if (s + 1 < STRIPES) {
            const float* dp = d + (m0 + RR) * KK;
            #pragma unroll
            for (int p = 0; p < 8; ++p)
                pv[p] = *(const float4*)(dp + (p * 256 + t) * 4);
        }

        // (2) compute current stripe: A from LDS (rows l15 and 16+l15),
        //     B resident; 32 MFMA/wave
        f32x4 acc[2][2];
        #pragma unroll
        for (int mt = 0; mt < 2; ++mt)
            #pragma unroll
            for (int nf = 0; nf < 2; ++nf)
                #pragma unroll
                for (int q = 0; q < 4; ++q) acc[mt][nf][q] = 0.f;

        #pragma unroll
        for (int kf = 0; kf < 8; ++kf) {
            const int cb = kf * 64 + lg * 16;
            const int xo = (l15 & 7) << 4;        // (16+l15)&7 == l15&7
            bf16x8 a0 = *(const bf16x8*)(cur + ((l15 * 512 + cb) ^ xo));
            bf16x8 a1 = *(const bf16x8*)(cur + (((16 + l15) * 512 + cb) ^ xo));
            #pragma unroll
            for (int nf = 0; nf < 2; ++nf) {
                acc[0][nf] = __builtin_amdgcn_mfma_f32_16x16x32_bf16(
                                 a0, bfrag[kf][nf], acc[0][nf], 0, 0, 0);
                acc[1][nf] = __builtin_amdgcn_mfma_f32_16x16x32_bf16(
                                 a1, bfrag[kf][nf], acc[1][nf], 0, 0, 0);
            }
        }

        // (3) C fragments -> LDS tile (scatter), then barrier
        #pragma unroll
        for (int mt = 0; mt < 2; ++mt)
            #pragma unroll
            for (int nf = 0; nf < 2; ++nf)
                #pragma unroll
                for (int q = 0; q < 4; ++q)
                    ldsC[(mt * 16 + lg * 4 + q) * HALFC + wid * 32 + nf * 16 + l15]
                        = acc[mt][nf][q];
        __syncthreads();

        // (4) stream C tile out LINEARLY: 4096 floats in 4 passes; per
        // wave-instruction 2 rows x 512 B contiguous (4 full cache lines).
        #pragma unroll
        for (int p = 0; p < 4; ++p) {
            const int e = p * 1024 + t * 4;          // element index in tile
            const float4 v = *(const float4*)(ldsC + e);
            *(float4*)(out + (m0 + (e >> 7)) * FF + half * HALFC + (e & 127)) = v;
        }

        // (5) convert + LDS-write pending A stripe into nxt
        if (s + 1 < STRIPES) {
            #pragma unroll
            for (int p = 0; p < 8; ++p) {
                const int row = p * 4 + srow0;
                int byte = row * 512 + scol;
                byte ^= (row & 7) << 4;
                short4v b;
                b.x = f2bf(pv[p].x); b.y = f2bf(pv[p].y);
                b.z = f2bf(pv[p].z); b.w = f2bf(pv[p].w);
                *(short4v*)(nxt + byte) = b;
            }
        }

        // (6) close the stripe
        __syncthreads();
    }
}

extern "C" void kernel_launch(void* const* d_in, const int* in_sizes, int n_in,
                              void* d_out, int out_size, void* d_ws, size_t ws_size,
                              hipStream_t stream) {
    const float* x  = (const float*)d_in[0];
    const float* d  = (const float*)d_in[1];
    const float* W  = (const float*)d_in[2];
    const int*   sx = (const int*)d_in[3];
    const int*   sy = (const int*)d_in[4];
    float* out = (float*)d_out;
    short* yp  = (short*)d_ws;   // 256*256 bf16 = 128 KB packed fragment buffer

    station_kernel<<<dim3(KK), dim3(FF), 0, stream>>>(x, W, sx, sy, yp);
    gemm_kernel<<<dim3(NBLK), dim3(256), 0, stream>>>(d, yp, out);
}

// Round 23
// 61.037 us; speedup vs baseline: 2.6603x; 1.2440x over previous
//
#include <hip/hip_runtime.h>

// Problem: H=W=384, F=K=256. M = 147456 rows.
// out[m,f] = sum_k d[m,k] * y[k,f],  y = x[stations] @ W  (256x256, tiny)
#define FF 256
#define KK 256
#define RR 32                  // rows per stripe
#define STRIPES 4              // stripes per block -> 128 rows/block
#define NBLK 2304              // (147456/128 rowgroups) * 2 col-halves
#define HALFC 128              // cols per block (half of FF)

typedef __attribute__((ext_vector_type(8))) short bf16x8;   // 8 bf16 (4 VGPR)
typedef __attribute__((ext_vector_type(4))) float f32x4;    // MFMA C/D frag
typedef __attribute__((ext_vector_type(4))) short short4v;  // 4 bf16 (8 B)

// float -> bf16 bits, round-to-nearest-even
__device__ inline short f2bf(float x) {
    unsigned u = __float_as_uint(x);
    unsigned r = u + 0x7FFFu + ((u >> 16) & 1u);
    return (short)(r >> 16);
}

// Kernel 1: y[k][f] = sum_j x[sx[k],sy[k],j] * W[j][f], stored bf16 in
// FRAGMENT ORDER so kernel-2 B loads are lane-contiguous 16B/lane:
//   idx(k,f) = ((f>>4)*8 + (k>>5))*512 + (((k>>3)&3)*16 + (f&15))*8 + (k&7)
__global__ __launch_bounds__(256) void station_kernel(
        const float* __restrict__ x, const float* __restrict__ W,
        const int* __restrict__ sx, const int* __restrict__ sy,
        short* __restrict__ yp) {
    __shared__ float xrow[FF];
    const int k = blockIdx.x;
    const int f = threadIdx.x;
    const long base = ((long)sx[k] * 384 + (long)sy[k]) * FF;
    xrow[f] = x[base + f];
    __syncthreads();
    float acc = 0.f;
    #pragma unroll 8
    for (int j = 0; j < FF; ++j)
        acc += xrow[j] * W[j * FF + f];   // coalesced across f
    const int idx = ((f >> 4) * 8 + (k >> 5)) * 512
                  + (((k >> 3) & 3) * 16 + (f & 15)) * 8 + (k & 7);
    yp[idx] = f2bf(acc);
}

// Kernel 2: R21 structure (proven components: bf16 XOR-swizzled A LDS,
// AGPR-parked bfrag, T14 issue-early/convert-late, LDS-linearized C) with
// NON-TEMPORAL C-stores (ext-vector type — HIP float4 rejected by builtin):
// out no longer write-allocates into L2/L3, so the 151 MB d input stays
// L3-resident across replays (FETCH 75 -> ~0-25 MB predicted).
__global__ __launch_bounds__(256, 3) void gemm_kernel(
        const float* __restrict__ d, const short* __restrict__ yp,
        float* __restrict__ out) {
    __shared__ __align__(16) short ldsA[2][RR * KK];   // 2 x 16 KB A, swizzled
    __shared__ __align__(16) float ldsC[RR * HALFC];   // 16 KB C staging
    const int t    = threadIdx.x;
    const int lane = t & 63;
    const int wid  = t >> 6;          // 0..3: 32-col slice within the half
    const int l15  = lane & 15;
    const int lg   = lane >> 4;       // 0..3: k-subgroup

    // Bijective XCD swizzle (NBLK % 8 == 0): row-sharing col-half pairs co-XCD.
    const int work = (blockIdx.x & 7) * (NBLK / 8) + (blockIdx.x >> 3);
    const int half = work & 1;                  // col half: 0..1 (128 cols)
    const long mblk = (long)(work >> 1) * (RR * STRIPES);

    char* lb0 = (char*)ldsA[0];
    char* lb1 = (char*)ldsA[1];

    // ---- B fragments: 16 x 16B/lane coalesced loads, once per block ----
    bf16x8 bfrag[8][2];
    #pragma unroll
    for (int kf = 0; kf < 8; ++kf)
        #pragma unroll
        for (int nf = 0; nf < 2; ++nf) {
            const int g = half * 8 + wid * 2 + nf;   // 16-col group 0..15
            bfrag[kf][nf] = *(const bf16x8*)(yp + ((g * 8 + kf) << 9) + (lane << 3));
        }
    // Anti-remat value barrier: keep them register/AGPR-resident.
    asm volatile("" :
        "+v"(bfrag[0][0]), "+v"(bfrag[0][1]), "+v"(bfrag[1][0]), "+v"(bfrag[1][1]),
        "+v"(bfrag[2][0]), "+v"(bfrag[2][1]), "+v"(bfrag[3][0]), "+v"(bfrag[3][1]),
        "+v"(bfrag[4][0]), "+v"(bfrag[4][1]), "+v"(bfrag[5][0]), "+v"(bfrag[5][1]),
        "+v"(bfrag[6][0]), "+v"(bfrag[6][1]), "+v"(bfrag[7][0]), "+v"(bfrag[7][1]));

    // staging geometry: pass p covers rows p*4 + (t>>6), lane writes 8B at
    // col-byte 8*(t&63). 8 passes x 256 thr x 4 floats = 8192 = 32 rows.
    const int srow0 = t >> 6;
    const int scol  = (t & 63) * 8;

    // ---- prologue: load + stage stripe 0 into buf0 ----
    float4 pv[8];
    {
        const float* dp = d + mblk * KK;
        #pragma unroll
        for (int p = 0; p < 8; ++p)
            pv[p] = *(const float4*)(dp + (p * 256 + t) * 4);
        #pragma unroll
        for (int p = 0; p < 8; ++p) {
            const int row = p * 4 + srow0;
            int byte = row * 512 + scol;
            byte ^= (row & 7) << 4;               // bank swizzle (G4)
            short4v b;
            b.x = f2bf(pv[p].x); b.y = f2bf(pv[p].y);
            b.z = f2bf(pv[p].z); b.w = f2bf(pv[p].w);
            *(short4v*)(lb0 + byte) = b;
        }
    }
    __syncthreads();

    for (int s = 0; s < STRIPES; ++s) {
        const long m0 = mblk + (long)s * RR;
        char* cur = (s & 1) ? lb1 : lb0;
        char* nxt = (s & 1) ? lb0 : lb1;

        // (1) issue next stripe's global loads — vmcnt waits land at stage
        if (s + 1 < STRIPES) {
            const float* dp = d + (m0 + RR) * KK;
            #pragma unroll
            for (int p = 0; p < 8; ++p)
                pv[p] = *(const float4*)(dp + (p * 256 + t) * 4);
        }

        // (2) compute current stripe: A from LDS (rows l15 and 16+l15),
        //     B resident; 32 MFMA/wave
        f32x4 acc[2][2];
        #pragma unroll
        for (int mt = 0; mt < 2; ++mt)
            #pragma unroll
            for (int nf = 0; nf < 2; ++nf)
                #pragma unroll
                for (int q = 0; q < 4; ++q) acc[mt][nf][q] = 0.f;

        #pragma unroll
        for (int kf = 0; kf < 8; ++kf) {
            const int cb = kf * 64 + lg * 16;
            const int xo = (l15 & 7) << 4;        // (16+l15)&7 == l15&7
            bf16x8 a0 = *(const bf16x8*)(cur + ((l15 * 512 + cb) ^ xo));
            bf16x8 a1 = *(const bf16x8*)(cur + (((16 + l15) * 512 + cb) ^ xo));
            #pragma unroll
            for (int nf = 0; nf < 2; ++nf) {
                acc[0][nf] = __builtin_amdgcn_mfma_f32_16x16x32_bf16(
                                 a0, bfrag[kf][nf], acc[0][nf], 0, 0, 0);
                acc[1][nf] = __builtin_amdgcn_mfma_f32_16x16x32_bf16(
                                 a1, bfrag[kf][nf], acc[1][nf], 0, 0, 0);
            }
        }

        // (3) C fragments -> LDS tile (scatter), then barrier
        #pragma unroll
        for (int mt = 0; mt < 2; ++mt)
            #pragma unroll
            for (int nf = 0; nf < 2; ++nf)
                #pragma unroll
                for (int q = 0; q < 4; ++q)
                    ldsC[(mt * 16 + lg * 4 + q) * HALFC + wid * 32 + nf * 16 + l15]
                        = acc[mt][nf][q];
        __syncthreads();

        // (4) stream C tile out LINEARLY with NON-TEMPORAL stores (no
        // write-allocate -> d stays L3-resident). Per wave-instruction:
        // 2 rows x 512 B contiguous (4 full cache lines).
        #pragma unroll
        for (int p = 0; p < 4; ++p) {
            const int e = p * 1024 + t * 4;          // element index in tile
            const f32x4 v = *(const f32x4*)(ldsC + e);
            __builtin_nontemporal_store(
                v, (f32x4*)(out + (m0 + (e >> 7)) * FF + half * HALFC + (e & 127)));
        }

        // (5) convert + LDS-write pending A stripe into nxt
        if (s + 1 < STRIPES) {
            #pragma unroll
            for (int p = 0; p < 8; ++p) {
                const int row = p * 4 + srow0;
                int byte = row * 512 + scol;
                byte ^= (row & 7) << 4;
                short4v b;
                b.x = f2bf(pv[p].x); b.y = f2bf(pv[p].y);
                b.z = f2bf(pv[p].z); b.w = f2bf(pv[p].w);
                *(short4v*)(nxt + byte) = b;
            }
        }

        // (6) close the stripe
        __syncthreads();
    }
}

extern "C" void kernel_launch(void* const* d_in, const int* in_sizes, int n_in,
                              void* d_out, int out_size, void* d_ws, size_t ws_size,
                              hipStream_t stream) {
    const float* x  = (const float*)d_in[0];
    const float* d  = (const float*)d_in[1];
    const float* W  = (const float*)d_in[2];
    const int*   sx = (const int*)d_in[3];
    const int*   sy = (const int*)d_in[4];
    float* out = (float*)d_out;
    short* yp  = (short*)d_ws;   // 256*256 bf16 = 128 KB packed fragment buffer

    station_kernel<<<dim3(KK), dim3(FF), 0, stream>>>(x, W, sx, sy, yp);
    gemm_kernel<<<dim3(NBLK), dim3(256), 0, stream>>>(d, yp, out);
}

// Round 24
// 60.148 us; speedup vs baseline: 2.6996x; 1.0148x over previous
//
#include <hip/hip_runtime.h>

// Problem: H=W=384, F=K=256. M = 147456 rows.
// out[m,f] = sum_k d[m,k] * y[k,f],  y = x[stations] @ W  (256x256, tiny)
#define FF 256
#define KK 256
#define RR 16                  // rows per stripe
#define STRIPES 4              // stripes per block -> 64 rows/block
#define NBLK 4608              // (147456/64 rowgroups) * 2 col-halves
#define HALFC 128              // cols per block (half of FF)

typedef __attribute__((ext_vector_type(8))) short bf16x8;   // 8 bf16 (4 VGPR)
typedef __attribute__((ext_vector_type(4))) float f32x4;    // MFMA C/D frag
typedef __attribute__((ext_vector_type(4))) short short4v;  // 4 bf16 (8 B)

// float -> bf16 bits, round-to-nearest-even
__device__ inline short f2bf(float x) {
    unsigned u = __float_as_uint(x);
    unsigned r = u + 0x7FFFu + ((u >> 16) & 1u);
    return (short)(r >> 16);
}

// Kernel 1: y[k][f] = sum_j x[sx[k],sy[k],j] * W[j][f], stored bf16 in
// FRAGMENT ORDER so kernel-2 B loads are lane-contiguous 16B/lane:
//   idx(k,f) = ((f>>4)*8 + (k>>5))*512 + (((k>>3)&3)*16 + (f&15))*8 + (k&7)
__global__ __launch_bounds__(256) void station_kernel(
        const float* __restrict__ x, const float* __restrict__ W,
        const int* __restrict__ sx, const int* __restrict__ sy,
        short* __restrict__ yp) {
    __shared__ float xrow[FF];
    const int k = blockIdx.x;
    const int f = threadIdx.x;
    const long base = ((long)sx[k] * 384 + (long)sy[k]) * FF;
    xrow[f] = x[base + f];
    __syncthreads();
    float acc = 0.f;
    #pragma unroll 8
    for (int j = 0; j < FF; ++j)
        acc += xrow[j] * W[j * FF + f];   // coalesced across f
    const int idx = ((f >> 4) * 8 + (k >> 5)) * 512
                  + (((k >> 3) & 3) * 16 + (f & 15)) * 8 + (k & 7);
    yp[idx] = f2bf(acc);
}

// Kernel 2: R20 structure (RR=16, best profiled dispatch 85.8us: bf16
// XOR-swizzled A LDS, AGPR-parked bfrag, T14 issue-early/convert-late,
// LDS-linearized C) + R23's NON-TEMPORAL C-stores (bench 75.9 -> 61.0):
// out skips write-allocate, d stays L3-resident across replays.
__global__ __launch_bounds__(256, 4) void gemm_kernel(
        const float* __restrict__ d, const short* __restrict__ yp,
        float* __restrict__ out) {
    __shared__ __align__(16) short ldsA[2][RR * KK];   // 2 x 8 KB A, swizzled
    __shared__ __align__(16) float ldsC[RR * HALFC];   // 8 KB C staging
    const int t    = threadIdx.x;
    const int lane = t & 63;
    const int wid  = t >> 6;          // 0..3: 32-col slice within the half
    const int l15  = lane & 15;
    const int lg   = lane >> 4;       // 0..3: k-subgroup

    // Bijective XCD swizzle (NBLK % 8 == 0): row-sharing col-half pairs co-XCD.
    const int work = (blockIdx.x & 7) * (NBLK / 8) + (blockIdx.x >> 3);
    const int half = work & 1;                  // col half: 0..1 (128 cols)
    const long mblk = (long)(work >> 1) * (RR * STRIPES);

    char* lb0 = (char*)ldsA[0];
    char* lb1 = (char*)ldsA[1];

    // ---- B fragments: 16 x 16B/lane coalesced loads, once per block ----
    bf16x8 bfrag[8][2];
    #pragma unroll
    for (int kf = 0; kf < 8; ++kf)
        #pragma unroll
        for (int nf = 0; nf < 2; ++nf) {
            const int g = half * 8 + wid * 2 + nf;   // 16-col group 0..15
            bfrag[kf][nf] = *(const bf16x8*)(yp + ((g * 8 + kf) << 9) + (lane << 3));
        }
    // Anti-remat value barrier: keep them register/AGPR-resident.
    asm volatile("" :
        "+v"(bfrag[0][0]), "+v"(bfrag[0][1]), "+v"(bfrag[1][0]), "+v"(bfrag[1][1]),
        "+v"(bfrag[2][0]), "+v"(bfrag[2][1]), "+v"(bfrag[3][0]), "+v"(bfrag[3][1]),
        "+v"(bfrag[4][0]), "+v"(bfrag[4][1]), "+v"(bfrag[5][0]), "+v"(bfrag[5][1]),
        "+v"(bfrag[6][0]), "+v"(bfrag[6][1]), "+v"(bfrag[7][0]), "+v"(bfrag[7][1]));

    // staging geometry: pass p covers rows p*4 + (t>>6), lane writes 8B at
    // col-byte 8*(t&63). 4 passes x 256 thr x 4 floats = 4096 = 16 rows.
    const int srow0 = t >> 6;
    const int scol  = (t & 63) * 8;

    // ---- prologue: load + stage stripe 0 into buf0 ----
    float4 pv[4];
    {
        const float* dp = d + mblk * KK;
        #pragma unroll
        for (int p = 0; p < 4; ++p)
            pv[p] = *(const float4*)(dp + (p * 256 + t) * 4);
        #pragma unroll
        for (int p = 0; p < 4; ++p) {
            const int row = p * 4 + srow0;
            int byte = row * 512 + scol;
            byte ^= (row & 7) << 4;               // bank swizzle (G4)
            short4v b;
            b.x = f2bf(pv[p].x); b.y = f2bf(pv[p].y);
            b.z = f2bf(pv[p].z); b.w = f2bf(pv[p].w);
            *(short4v*)(lb0 + byte) = b;
        }
    }
    __syncthreads();

    for (int s = 0; s < STRIPES; ++s) {
        const long m0 = mblk + (long)s * RR;
        char* cur = (s & 1) ? lb1 : lb0;
        char* nxt = (s & 1) ? lb0 : lb1;

        // (1) issue next stripe's global loads — vmcnt waits land at stage
        if (s + 1 < STRIPES) {
            const float* dp = d + (m0 + RR) * KK;
            #pragma unroll
            for (int p = 0; p < 4; ++p)
                pv[p] = *(const float4*)(dp + (p * 256 + t) * 4);
        }

        // (2) compute current stripe: A from LDS, B resident
        f32x4 acc[2];
        #pragma unroll
        for (int nf = 0; nf < 2; ++nf)
            #pragma unroll
            for (int q = 0; q < 4; ++q) acc[nf][q] = 0.f;

        #pragma unroll
        for (int kf = 0; kf < 8; ++kf) {
            const int cb = kf * 64 + lg * 16;
            const int xo = (l15 & 7) << 4;
            bf16x8 a0 = *(const bf16x8*)(cur + ((l15 * 512 + cb) ^ xo));
            #pragma unroll
            for (int nf = 0; nf < 2; ++nf)
                acc[nf] = __builtin_amdgcn_mfma_f32_16x16x32_bf16(
                              a0, bfrag[kf][nf], acc[nf], 0, 0, 0);
        }

        // (3) C fragments -> LDS tile (scatter), then barrier
        #pragma unroll
        for (int nf = 0; nf < 2; ++nf)
            #pragma unroll
            for (int q = 0; q < 4; ++q)
                ldsC[(lg * 4 + q) * HALFC + wid * 32 + nf * 16 + l15]
                    = acc[nf][q];
        __syncthreads();

        // (4) stream C tile out LINEARLY with NON-TEMPORAL stores: per
        // wave-instruction 2 rows x 512 B contiguous, no write-allocate.
        #pragma unroll
        for (int p = 0; p < 2; ++p) {
            const int e = p * 1024 + t * 4;          // element index in tile
            const f32x4 v = *(const f32x4*)(ldsC + e);
            __builtin_nontemporal_store(
                v, (f32x4*)(out + (m0 + (e >> 7)) * FF + half * HALFC + (e & 127)));
        }

        // (5) convert + LDS-write pending A stripe into nxt
        if (s + 1 < STRIPES) {
            #pragma unroll
            for (int p = 0; p < 4; ++p) {
                const int row = p * 4 + srow0;
                int byte = row * 512 + scol;
                byte ^= (row & 7) << 4;
                short4v b;
                b.x = f2bf(pv[p].x); b.y = f2bf(pv[p].y);
                b.z = f2bf(pv[p].z); b.w = f2bf(pv[p].w);
                *(short4v*)(nxt + byte) = b;
            }
        }

        // (6) close the stripe
        __syncthreads();
    }
}

extern "C" void kernel_launch(void* const* d_in, const int* in_sizes, int n_in,
                              void* d_out, int out_size, void* d_ws, size_t ws_size,
                              hipStream_t stream) {
    const float* x  = (const float*)d_in[0];
    const float* d  = (const float*)d_in[1];
    const float* W  = (const float*)d_in[2];
    const int*   sx = (const int*)d_in[3];
    const int*   sy = (const int*)d_in[4];
    float* out = (float*)d_out;
    short* yp  = (short*)d_ws;   // 256*256 bf16 = 128 KB packed fragment buffer

    station_kernel<<<dim3(KK), dim3(FF), 0, stream>>>(x, W, sx, sy, yp);
    gemm_kernel<<<dim3(NBLK), dim3(256), 0, stream>>>(d, yp, out);
}